// Round 3
// baseline (663.245 us; speedup 1.0000x reference)
//
#include <hip/hip_runtime.h>
#include <stdint.h>
#include <stddef.h>

// ---------------------------------------------------------------------------
// CalderaQuantizedLinear: out = FWHT( FWHT(x*SU) @ (Wq + Wl^T Wr + Lft Rft)^T ) * SV
// Strategy: fold low-rank terms + Wq into one combined bf16 weight W'[4096][4096],
// then one 8192x4096x4096 bf16 MFMA GEMM (m97 structure + T2 swizzle).
// ---------------------------------------------------------------------------

typedef __attribute__((ext_vector_type(8))) __bf16 bf16x8;
typedef __attribute__((ext_vector_type(4))) float f32x4;

#define DEVFN static __device__ __forceinline__

typedef const __attribute__((address_space(1))) void* as1cvp;
typedef __attribute__((address_space(3))) void* as3vp;

DEVFN void async_g2l16(const void* g, void* l) {
  __builtin_amdgcn_global_load_lds((as1cvp)g, (as3vp)l, 16, 0, 0);
}

// ---------------- 4096-point FWHT as radix-16^3 ----------------
DEVFN void fwht16(float* v) {
  #pragma unroll
  for (int h = 1; h < 16; h <<= 1) {
    #pragma unroll
    for (int i = 0; i < 16; ++i) {
      if ((i & h) == 0) {
        float a = v[i], b = v[i + h];
        v[i] = a + b;
        v[i + h] = a - b;
      }
    }
  }
}

DEVFN int padi(int i) { return i + (i >> 4) + (i >> 8); }  // conflict-free LDS pad

// MODE 0: in = x (f32), multiply sgn (SU) BEFORE transform, write bf16 to outb.
// MODE 1: in = out (f32, in place), multiply sgn (SV) AFTER transform, write f32.
template<int MODE>
__global__ __launch_bounds__(256)
void fwht_rows(const float* in, const float* __restrict__ sgn,
               __bf16* __restrict__ outb, float* outf)
{
  __shared__ float s[4366];  // 4096 + pad
  const int row = blockIdx.x;
  const int t = threadIdx.x;
  const float* src = in + (size_t)row * 4096;
  float v[16];

  // round 1: thread owns elements [16t, 16t+16)  (bits 0-3)
  #pragma unroll
  for (int j4 = 0; j4 < 4; ++j4) {
    f32x4 xv = *(const f32x4*)(src + t * 16 + j4 * 4);
    #pragma unroll
    for (int q = 0; q < 4; ++q) v[j4 * 4 + q] = xv[q];
  }
  if (MODE == 0) {
    #pragma unroll
    for (int j = 0; j < 16; ++j) v[j] *= sgn[t * 16 + j];
  }
  fwht16(v);
  {
    const int base = t * 17 + (t >> 4);  // == padi(16t), pad constant within the 16
    #pragma unroll
    for (int j = 0; j < 16; ++j) s[base + j] = v[j];
  }
  __syncthreads();

  // round 2: stride-16 groups (bits 4-7)
  const int base2 = (t & 15) + ((t >> 4) << 8);
  #pragma unroll
  for (int i = 0; i < 16; ++i) v[i] = s[padi(base2 + (i << 4))];
  fwht16(v);
  #pragma unroll
  for (int i = 0; i < 16; ++i) s[padi(base2 + (i << 4))] = v[i];
  __syncthreads();

  // round 3: stride-256 groups (bits 8-11)
  #pragma unroll
  for (int i = 0; i < 16; ++i) v[i] = s[padi(t + (i << 8))];
  fwht16(v);

  if (MODE == 0) {
    #pragma unroll
    for (int i = 0; i < 16; ++i)
      outb[(size_t)row * 4096 + t + (i << 8)] = (__bf16)(v[i] * 0.015625f);
  } else {
    #pragma unroll
    for (int i = 0; i < 16; ++i) {
      int c = t + (i << 8);
      outf[(size_t)row * 4096 + c] = v[i] * 0.015625f * sgn[c];
    }
  }
}

// ---------------- build Ut[4096][128], Vt[4096][128] (bf16) ----------------
// Ut[j][r] = r<64 ? 1.1*grid[L_idxs[r][j/8]][j%8] : L_ft[j][r-64]
// Vt[k][r] = r<64 ? 1.05*grid[R_idxs[r][k/8]][k%8] : R_ft[r-64][k]
__global__ __launch_bounds__(256)
void prep_uv(const float* __restrict__ grid8,
             const float* __restrict__ Lft, const float* __restrict__ Rft,
             const int* __restrict__ Lidx, const int* __restrict__ Ridx,
             __bf16* __restrict__ Ut, __bf16* __restrict__ Vt)
{
  int tid = blockIdx.x * 256 + threadIdx.x;
  const int half = 4096 * 128;
  bool isV = tid >= half;
  int e = isV ? tid - half : tid;
  int j = e >> 7;    // 0..4095
  int r = e & 127;   // 0..127
  float v;
  if (!isV) {
    if (r < 64) v = 1.1f * grid8[(size_t)Lidx[r * 512 + (j >> 3)] * 8 + (j & 7)];
    else        v = Lft[(size_t)j * 64 + (r - 64)];
    Ut[e] = (__bf16)v;
  } else {
    if (r < 64) v = 1.05f * grid8[(size_t)Ridx[r * 512 + (j >> 3)] * 8 + (j & 7)];
    else        v = Rft[(size_t)(r - 64) * 4096 + j];
    Vt[e] = (__bf16)v;
  }
}

// ---------------- GEMM: C[M,N] = A[M,K] * B[N,K]^T (both bf16, K contiguous) ---
// 128x128 tile, 4 waves (2x2 of 64x64), BK=64, mfma_f32_16x16x32_bf16.
// T2 swizzle: linear LDS dest for global_load_lds, inverse-swizzled global
// source, swizzled ds_read (rule #21).
// EPI 0: write f32 to Cf (main GEMM).
// EPI 1: add 0.9*dequant(Wq) and write bf16 to Cb (weight-combine GEMM).
template<int K, int EPI>
__global__ __launch_bounds__(256)
void gemm_bt(const __bf16* __restrict__ A, const __bf16* __restrict__ B,
             float* __restrict__ Cf, __bf16* __restrict__ Cb,
             const int* __restrict__ Qidx, const float* __restrict__ grid8,
             int Nn, int nbx)
{
  __shared__ __bf16 sA[128 * 64];
  __shared__ __bf16 sB[128 * 64];

  // XCD-aware swizzle (gridDim.x divisible by 8)
  const int nwg = gridDim.x;
  const int orig = blockIdx.x;
  const int cpx = nwg >> 3;
  const int wg = (orig & 7) * cpx + (orig >> 3);
  const int bm = wg / nbx, bn = wg % nbx;

  const int t = threadIdx.x;
  const int lane = t & 63;
  const int w = t >> 6;
  const int wr = w >> 1, wc = w & 1;

  const int aRow0 = bm * 128;
  const int bRow0 = bn * 128;

  f32x4 acc[4][4] = {};

  #pragma unroll 1
  for (int k0 = 0; k0 < K; k0 += 64) {
    // stage A and B tiles: 128 rows x 64 cols bf16 each; 4 issues of 16B/thread
    #pragma unroll
    for (int i = 0; i < 4; ++i) {
      int u = i * 256 + t;          // linear 16B store unit
      int row = u >> 3, cs = u & 7;
      int c = cs ^ (row & 7);       // inverse-swizzled source chunk
      async_g2l16(A + (size_t)(aRow0 + row) * K + k0 + c * 8, &sA[u * 8]);
      async_g2l16(B + (size_t)(bRow0 + row) * K + k0 + c * 8, &sB[u * 8]);
    }
    asm volatile("s_waitcnt vmcnt(0)" ::: "memory");
    __syncthreads();

    bf16x8 a[4][2], b[4][2];
    #pragma unroll
    for (int m = 0; m < 4; ++m) {
      #pragma unroll
      for (int kk = 0; kk < 2; ++kk) {
        int c = kk * 4 + (lane >> 4);
        int rowA = wr * 64 + m * 16 + (lane & 15);
        int uA = rowA * 8 + (c ^ (rowA & 7));
        a[m][kk] = *(const bf16x8*)&sA[uA * 8];
        int rowB = wc * 64 + m * 16 + (lane & 15);
        int uB = rowB * 8 + (c ^ (rowB & 7));
        b[m][kk] = *(const bf16x8*)&sB[uB * 8];
      }
    }
    #pragma unroll
    for (int kk = 0; kk < 2; ++kk)
      #pragma unroll
      for (int m = 0; m < 4; ++m)
        #pragma unroll
        for (int n = 0; n < 4; ++n)
          acc[m][n] = __builtin_amdgcn_mfma_f32_16x16x32_bf16(
              a[m][kk], b[n][kk], acc[m][n], 0, 0, 0);
    __syncthreads();
  }

  // epilogue: C/D layout col=lane&15, row=(lane>>4)*4+q  (m89/m91 verified)
  #pragma unroll
  for (int m = 0; m < 4; ++m) {
    #pragma unroll
    for (int n = 0; n < 4; ++n) {
      int gr = aRow0 + wr * 64 + m * 16 + ((lane >> 4) << 2);
      int gc = bRow0 + wc * 64 + n * 16 + (lane & 15);
      #pragma unroll
      for (int q = 0; q < 4; ++q) {
        float v = acc[m][n][q];
        if constexpr (EPI == 0) {
          Cf[(size_t)(gr + q) * Nn + gc] = v;
        } else {
          int idx = Qidx[(size_t)(gr + q) * (Nn >> 3) + (gc >> 3)];
          v += 0.9f * grid8[(size_t)idx * 8 + (gc & 7)];
          Cb[(size_t)(gr + q) * Nn + gc] = (__bf16)v;
        }
      }
    }
  }
}

// ---------------------------------------------------------------------------
extern "C" void kernel_launch(void* const* d_in, const int* in_sizes, int n_in,
                              void* d_out, int out_size, void* d_ws, size_t ws_size,
                              hipStream_t stream) {
  const float* x    = (const float*)d_in[0];
  const float* SU   = (const float*)d_in[1];
  const float* SV   = (const float*)d_in[2];
  const float* grid = (const float*)d_in[3];
  const float* Lft  = (const float*)d_in[4];
  const float* Rft  = (const float*)d_in[5];
  const int*   Qidx = (const int*)d_in[6];
  const int*   Ridx = (const int*)d_in[7];
  const int*   Lidx = (const int*)d_in[8];
  float* out = (float*)d_out;

  char* ws = (char*)d_ws;
  __bf16* xh = (__bf16*)ws;                               // 8192x4096 bf16 = 64 MiB
  __bf16* Wc = (__bf16*)(ws + ((size_t)64 << 20));        // 4096x4096 bf16 = 32 MiB
  __bf16* Ut = (__bf16*)(ws + ((size_t)96 << 20));        // 4096x128  bf16 =  1 MiB
  __bf16* Vt = (__bf16*)(ws + ((size_t)97 << 20));        // 4096x128  bf16 =  1 MiB

  // 1. low-rank factors -> Ut, Vt
  prep_uv<<<4096, 256, 0, stream>>>(grid, Lft, Rft, Lidx, Ridx, Ut, Vt);
  // 2. xh = FWHT(x * SU), bf16
  fwht_rows<0><<<8192, 256, 0, stream>>>(x, SU, xh, nullptr);
  // 3. W' = Ut @ Vt^T + 0.9*dequant(Wq)  (bf16)
  gemm_bt<128, 1><<<1024, 256, 0, stream>>>(Ut, Vt, nullptr, Wc, Qidx, grid, 4096, 32);
  // 4. out = xh @ W'^T (f32)
  gemm_bt<4096, 0><<<2048, 256, 0, stream>>>(xh, Wc, out, nullptr, nullptr, nullptr, 4096, 32);
  // 5. out = FWHT(out) * SV, in place
  fwht_rows<1><<<8192, 256, 0, stream>>>(out, SV, nullptr, out);
}

// Round 4
// 589.641 us; speedup vs baseline: 1.1248x; 1.1248x over previous
//
#include <hip/hip_runtime.h>
#include <stdint.h>
#include <stddef.h>

// ---------------------------------------------------------------------------
// CalderaQuantizedLinear: out = FWHT( FWHT(x*SU) @ (Wq + Wl^T Wr + Lft Rft)^T ) * SV
// Fold low-rank terms + Wq into one combined bf16 weight W'[4096][4096], then
// one 8192x4096x4096 bf16 MFMA GEMM.
// R4: main GEMM -> 256x256 tile, BK=32, ring-4 LDS, counted vmcnt(8) pipeline.
//     FWHT kernels -> vectorized final stores via extra LDS round-trip.
// ---------------------------------------------------------------------------

typedef __attribute__((ext_vector_type(8))) __bf16 bf16x8;
typedef __attribute__((ext_vector_type(4))) float f32x4;

#define DEVFN static __device__ __forceinline__

typedef const __attribute__((address_space(1))) void* as1cvp;
typedef __attribute__((address_space(3))) void* as3vp;

DEVFN void async_g2l16(const void* g, void* l) {
  __builtin_amdgcn_global_load_lds((as1cvp)g, (as3vp)l, 16, 0, 0);
}

// ---------------- 4096-point FWHT as radix-16^3 ----------------
DEVFN void fwht16(float* v) {
  #pragma unroll
  for (int h = 1; h < 16; h <<= 1) {
    #pragma unroll
    for (int i = 0; i < 16; ++i) {
      if ((i & h) == 0) {
        float a = v[i], b = v[i + h];
        v[i] = a + b;
        v[i + h] = a - b;
      }
    }
  }
}

DEVFN int padi(int i) { return i + (i >> 4) + (i >> 8); }  // conflict-free LDS pad

// MODE 0: in = x (f32), multiply sgn (SU) BEFORE transform, write bf16 (x 1/64).
// MODE 1: in = f32 (d_out in place), multiply sgn (SV) AFTER transform, write f32.
// Final store: extra LDS round-trip so thread t owns contiguous [16t,16t+16).
template<int MODE>
__global__ __launch_bounds__(256)
void fwht_rows(const float* in, const float* __restrict__ sgn,
               __bf16* __restrict__ outb, float* outf)
{
  __shared__ float s[4366];  // 4096 + pad
  const int row = blockIdx.x;
  const int t = threadIdx.x;
  const int base1 = t * 17 + (t >> 4);  // == padi(16t); padi(16t+j)=base1+j for j<16
  float v[16];

  // round 1: thread owns elements [16t, 16t+16)  (bits 0-3)
  {
    const float* src = in + (size_t)row * 4096 + t * 16;
    #pragma unroll
    for (int j4 = 0; j4 < 4; ++j4) {
      f32x4 xv = *(const f32x4*)(src + j4 * 4);
      #pragma unroll
      for (int q = 0; q < 4; ++q) v[j4 * 4 + q] = xv[q];
    }
  }
  if (MODE == 0) {
    const f32x4* sg4 = (const f32x4*)(sgn + t * 16);
    #pragma unroll
    for (int j4 = 0; j4 < 4; ++j4) {
      f32x4 sv = sg4[j4];
      #pragma unroll
      for (int q = 0; q < 4; ++q) v[j4 * 4 + q] *= sv[q];
    }
  }
  fwht16(v);
  #pragma unroll
  for (int j = 0; j < 16; ++j) s[base1 + j] = v[j];
  __syncthreads();

  // round 2: stride-16 groups (bits 4-7)
  const int base2 = (t & 15) + ((t >> 4) << 8);
  #pragma unroll
  for (int i = 0; i < 16; ++i) v[i] = s[padi(base2 + (i << 4))];
  fwht16(v);
  #pragma unroll
  for (int i = 0; i < 16; ++i) s[padi(base2 + (i << 4))] = v[i];
  __syncthreads();

  // round 3: stride-256 groups (bits 8-11)
  #pragma unroll
  for (int i = 0; i < 16; ++i) v[i] = s[padi(t + (i << 8))];
  fwht16(v);
  #pragma unroll
  for (int i = 0; i < 16; ++i) s[padi(t + (i << 8))] = v[i];
  __syncthreads();

  // vectorized store: thread t reads contiguous LDS [base1, base1+16)
  if (MODE == 0) {
    bf16x8 o0, o1;
    #pragma unroll
    for (int j = 0; j < 8; ++j) o0[j] = (__bf16)(s[base1 + j] * 0.015625f);
    #pragma unroll
    for (int j = 0; j < 8; ++j) o1[j] = (__bf16)(s[base1 + 8 + j] * 0.015625f);
    __bf16* dst = outb + (size_t)row * 4096 + t * 16;
    *(bf16x8*)dst = o0;
    *(bf16x8*)(dst + 8) = o1;
  } else {
    const f32x4* sg4 = (const f32x4*)(sgn + t * 16);
    float* dst = outf + (size_t)row * 4096 + t * 16;
    #pragma unroll
    for (int j4 = 0; j4 < 4; ++j4) {
      f32x4 sv = sg4[j4];
      f32x4 ov;
      #pragma unroll
      for (int q = 0; q < 4; ++q) ov[q] = s[base1 + j4 * 4 + q] * 0.015625f * sv[q];
      *(f32x4*)(dst + j4 * 4) = ov;
    }
  }
}

// ---------------- build Ut[4096][128], Vt[4096][128] (bf16) ----------------
__global__ __launch_bounds__(256)
void prep_uv(const float* __restrict__ grid8,
             const float* __restrict__ Lft, const float* __restrict__ Rft,
             const int* __restrict__ Lidx, const int* __restrict__ Ridx,
             __bf16* __restrict__ Ut, __bf16* __restrict__ Vt)
{
  int tid = blockIdx.x * 256 + threadIdx.x;
  const int half = 4096 * 128;
  bool isV = tid >= half;
  int e = isV ? tid - half : tid;
  int j = e >> 7;    // 0..4095
  int r = e & 127;   // 0..127
  float v;
  if (!isV) {
    if (r < 64) v = 1.1f * grid8[(size_t)Lidx[r * 512 + (j >> 3)] * 8 + (j & 7)];
    else        v = Lft[(size_t)j * 64 + (r - 64)];
    Ut[e] = (__bf16)v;
  } else {
    if (r < 64) v = 1.05f * grid8[(size_t)Ridx[r * 512 + (j >> 3)] * 8 + (j & 7)];
    else        v = Rft[(size_t)(r - 64) * 4096 + j];
    Vt[e] = (__bf16)v;
  }
}

// ---------------- combine GEMM (proven m97-style, K=128): W' builder --------
// C[M,N] = A[M,K]*B[N,K]^T + 0.9*dequant(Wq), bf16 out.
template<int K>
__global__ __launch_bounds__(256)
void gemm_bt(const __bf16* __restrict__ A, const __bf16* __restrict__ B,
             __bf16* __restrict__ Cb,
             const int* __restrict__ Qidx, const float* __restrict__ grid8,
             int Nn, int nbx)
{
  __shared__ __bf16 sA[128 * 64];
  __shared__ __bf16 sB[128 * 64];

  const int nwg = gridDim.x;
  const int orig = blockIdx.x;
  const int cpx = nwg >> 3;
  const int wg = (orig & 7) * cpx + (orig >> 3);
  const int bm = wg / nbx, bn = wg % nbx;

  const int t = threadIdx.x;
  const int lane = t & 63;
  const int w = t >> 6;
  const int wr = w >> 1, wc = w & 1;

  const int aRow0 = bm * 128;
  const int bRow0 = bn * 128;

  f32x4 acc[4][4] = {};

  #pragma unroll 1
  for (int k0 = 0; k0 < K; k0 += 64) {
    #pragma unroll
    for (int i = 0; i < 4; ++i) {
      int u = i * 256 + t;
      int rowu = u >> 3, cs = u & 7;
      int c = cs ^ (rowu & 7);
      async_g2l16(A + (size_t)(aRow0 + rowu) * K + k0 + c * 8, &sA[u * 8]);
      async_g2l16(B + (size_t)(bRow0 + rowu) * K + k0 + c * 8, &sB[u * 8]);
    }
    asm volatile("s_waitcnt vmcnt(0)" ::: "memory");
    __syncthreads();

    bf16x8 a[4][2], b[4][2];
    #pragma unroll
    for (int m = 0; m < 4; ++m) {
      #pragma unroll
      for (int kk = 0; kk < 2; ++kk) {
        int c = kk * 4 + (lane >> 4);
        int rowA = wr * 64 + m * 16 + (lane & 15);
        int uA = rowA * 8 + (c ^ (rowA & 7));
        a[m][kk] = *(const bf16x8*)&sA[uA * 8];
        int rowB = wc * 64 + m * 16 + (lane & 15);
        int uB = rowB * 8 + (c ^ (rowB & 7));
        b[m][kk] = *(const bf16x8*)&sB[uB * 8];
      }
    }
    #pragma unroll
    for (int kk = 0; kk < 2; ++kk)
      #pragma unroll
      for (int m = 0; m < 4; ++m)
        #pragma unroll
        for (int n = 0; n < 4; ++n)
          acc[m][n] = __builtin_amdgcn_mfma_f32_16x16x32_bf16(
              a[m][kk], b[n][kk], acc[m][n], 0, 0, 0);
    __syncthreads();
  }

  #pragma unroll
  for (int m = 0; m < 4; ++m) {
    #pragma unroll
    for (int n = 0; n < 4; ++n) {
      int gr = aRow0 + wr * 64 + m * 16 + ((lane >> 4) << 2);
      int gc = bRow0 + wc * 64 + n * 16 + (lane & 15);
      #pragma unroll
      for (int q = 0; q < 4; ++q) {
        float v = acc[m][n][q];
        int idx = Qidx[(size_t)(gr + q) * (Nn >> 3) + (gc >> 3)];
        v += 0.9f * grid8[(size_t)idx * 8 + (gc & 7)];
        Cb[(size_t)(gr + q) * Nn + gc] = (__bf16)v;
      }
    }
  }
}

// ---------------- main GEMM: 256x256 tile, BK=32, ring-4, counted vmcnt ------
// C[M,N] = A[M,K]*B[N,K]^T, f32 out. 512 threads = 8 waves (2M x 4N).
// Wave output 128x64. acc[8][4] f32x4. LDS: 4 ring bufs x (A 16K + B 16K) = 128K.
// LDS layout per 256x32 tile: paired rows -> [128 prow][8 slot] 16B units,
// slot = ((r&1)*4 + k8) ^ (prow&7)  (2-way bank aliasing = free; verified-0
// conflicts for this swizzle family in R3 counters).
// Pipeline: stage tile t+3 at top of iter t; vmcnt(8) + 1 barrier per tile
// (tiles t+2, t+3 stay in flight across the barrier -> T3/T4 mechanism).
template<int NT>   // K = NT*32
__global__ __launch_bounds__(512, 2)
void gemm256(const __bf16* __restrict__ A, const __bf16* __restrict__ B,
             float* __restrict__ Cf, int Nn, int nbx)
{
  constexpr int K = NT * 32;
  __shared__ __bf16 lds[4 * 2 * 8192];  // [buf][mat] 8192 bf16 each

  const int nwg = gridDim.x;            // divisible by 8
  const int orig = blockIdx.x;
  const int cpx = nwg >> 3;
  const int wg = (orig & 7) * cpx + (orig >> 3);
  const int bm = wg / nbx, bn = wg % nbx;

  const int tid = threadIdx.x;
  const int lane = tid & 63;
  const int wid = tid >> 6;
  const int wm = wid >> 2;              // 0..1
  const int wn = wid & 3;               // 0..3

  const int aRow0 = bm * 256;
  const int bRow0 = bn * 256;

  // staging: tile t -> buf t&3; 2 insts per matrix, 16B/thread each
  auto stage = [&](int t) {
    __bf16* dA = &lds[((t & 3) * 2 + 0) * 8192];
    __bf16* dB = &lds[((t & 3) * 2 + 1) * 8192];
    const __bf16* sAg = A + (size_t)aRow0 * K + t * 32;
    const __bf16* sBg = B + (size_t)bRow0 * K + t * 32;
    #pragma unroll
    for (int i = 0; i < 2; ++i) {
      int u = i * 512 + tid;
      int prow = u >> 3, slot = u & 7;
      int chunk = slot ^ (prow & 7);
      int r = 2 * prow + (chunk >> 2);
      int k8 = chunk & 3;
      async_g2l16(sAg + (size_t)r * K + k8 * 8, dA + u * 8);
    }
    #pragma unroll
    for (int i = 0; i < 2; ++i) {
      int u = i * 512 + tid;
      int prow = u >> 3, slot = u & 7;
      int chunk = slot ^ (prow & 7);
      int r = 2 * prow + (chunk >> 2);
      int k8 = chunk & 3;
      async_g2l16(sBg + (size_t)r * K + k8 * 8, dB + u * 8);
    }
  };

  const int k8l = lane >> 4;            // 0..3
  const int rl = lane & 15;

  f32x4 acc[8][4] = {};

  // prologue: stage tiles 0,1,2; wait tile 0 (leave 8 loads in flight)
  stage(0); stage(1); stage(2);
  asm volatile("s_waitcnt vmcnt(8)" ::: "memory");
  __syncthreads();

  #pragma unroll 1
  for (int t = 0; t < NT; ++t) {
    if (t + 3 < NT) stage(t + 3);

    const __bf16* bufA = &lds[((t & 3) * 2 + 0) * 8192];
    const __bf16* bufB = &lds[((t & 3) * 2 + 1) * 8192];

    bf16x8 af[8], bfr[4];
    #pragma unroll
    for (int m = 0; m < 8; ++m) {
      int r = wm * 128 + m * 16 + rl;
      int prow = r >> 1;
      int slot = (((r & 1) << 2) | k8l) ^ (prow & 7);
      af[m] = *(const bf16x8*)(bufA + (prow * 8 + slot) * 8);
    }
    #pragma unroll
    for (int n = 0; n < 4; ++n) {
      int r = wn * 64 + n * 16 + rl;
      int prow = r >> 1;
      int slot = (((r & 1) << 2) | k8l) ^ (prow & 7);
      bfr[n] = *(const bf16x8*)(bufB + (prow * 8 + slot) * 8);
    }

    __builtin_amdgcn_s_setprio(1);
    #pragma unroll
    for (int m = 0; m < 8; ++m)
      #pragma unroll
      for (int n = 0; n < 4; ++n)
        acc[m][n] = __builtin_amdgcn_mfma_f32_16x16x32_bf16(
            af[m], bfr[n], acc[m][n], 0, 0, 0);
    __builtin_amdgcn_s_setprio(0);

    // counted vmcnt: ensure tile t+1 resident; keep tiles t+2, t+3 in flight
    if (t + 3 < NT)      asm volatile("s_waitcnt vmcnt(8)" ::: "memory");
    else if (t + 2 < NT) asm volatile("s_waitcnt vmcnt(4)" ::: "memory");
    else if (t + 1 < NT) asm volatile("s_waitcnt vmcnt(0)" ::: "memory");
    __syncthreads();
  }

  // epilogue: C/D layout col=lane&15, row=(lane>>4)*4+q
  #pragma unroll
  for (int m = 0; m < 8; ++m) {
    #pragma unroll
    for (int n = 0; n < 4; ++n) {
      int gr = aRow0 + wm * 128 + m * 16 + ((lane >> 4) << 2);
      int gc = bRow0 + wn * 64 + n * 16 + (lane & 15);
      #pragma unroll
      for (int q = 0; q < 4; ++q)
        Cf[(size_t)(gr + q) * Nn + gc] = acc[m][n][q];
    }
  }
}

// ---------------------------------------------------------------------------
extern "C" void kernel_launch(void* const* d_in, const int* in_sizes, int n_in,
                              void* d_out, int out_size, void* d_ws, size_t ws_size,
                              hipStream_t stream) {
  const float* x    = (const float*)d_in[0];
  const float* SU   = (const float*)d_in[1];
  const float* SV   = (const float*)d_in[2];
  const float* grid = (const float*)d_in[3];
  const float* Lft  = (const float*)d_in[4];
  const float* Rft  = (const float*)d_in[5];
  const int*   Qidx = (const int*)d_in[6];
  const int*   Ridx = (const int*)d_in[7];
  const int*   Lidx = (const int*)d_in[8];
  float* out = (float*)d_out;

  char* ws = (char*)d_ws;
  __bf16* xh = (__bf16*)ws;                               // 8192x4096 bf16 = 64 MiB
  __bf16* Wc = (__bf16*)(ws + ((size_t)64 << 20));        // 4096x4096 bf16 = 32 MiB
  __bf16* Ut = (__bf16*)(ws + ((size_t)96 << 20));        // 4096x128  bf16 =  1 MiB
  __bf16* Vt = (__bf16*)(ws + ((size_t)97 << 20));        // 4096x128  bf16 =  1 MiB

  // 1. low-rank factors -> Ut, Vt
  prep_uv<<<4096, 256, 0, stream>>>(grid, Lft, Rft, Lidx, Ridx, Ut, Vt);
  // 2. xh = FWHT(x * SU), bf16
  fwht_rows<0><<<8192, 256, 0, stream>>>(x, SU, xh, nullptr);
  // 3. W' = Ut @ Vt^T + 0.9*dequant(Wq)  (bf16)
  gemm_bt<128><<<1024, 256, 0, stream>>>(Ut, Vt, Wc, Qidx, grid, 4096, 32);
  // 4. out = xh @ W'^T (f32), 256^2 tile ring-4 pipeline
  gemm256<128><<<512, 512, 0, stream>>>(xh, Wc, out, 4096, 16);
  // 5. out = FWHT(out) * SV, in place
  fwht_rows<1><<<8192, 256, 0, stream>>>(out, SV, nullptr, out);
}

// Round 5
// 572.009 us; speedup vs baseline: 1.1595x; 1.0308x over previous
//
#include <hip/hip_runtime.h>
#include <stdint.h>
#include <stddef.h>

// ---------------------------------------------------------------------------
// CalderaQuantizedLinear: out = FWHT( FWHT(x*SU) @ (Wq + Wl^T Wr + Lft Rft)^T ) * SV
// Fold low-rank terms + Wq into one combined bf16 weight W'[4096][4096], then
// one 8192x4096x4096 bf16 MFMA GEMM.
// R5: main GEMM -> true 8-phase (raw s_barrier, counted vmcnt, setprio).
//     FWHT -> 4 rows/block with register prefetch; direct coalesced stores.
// ---------------------------------------------------------------------------

typedef __attribute__((ext_vector_type(8))) __bf16 bf16x8;
typedef __attribute__((ext_vector_type(4))) float f32x4;

#define DEVFN static __device__ __forceinline__

typedef const __attribute__((address_space(1))) void* as1cvp;
typedef __attribute__((address_space(3))) void* as3vp;

DEVFN void async_g2l16(const void* g, void* l) {
  __builtin_amdgcn_global_load_lds((as1cvp)g, (as3vp)l, 16, 0, 0);
}

// ---------------- 4096-point FWHT as radix-16^3 ----------------
DEVFN void fwht16(float* v) {
  #pragma unroll
  for (int h = 1; h < 16; h <<= 1) {
    #pragma unroll
    for (int i = 0; i < 16; ++i) {
      if ((i & h) == 0) {
        float a = v[i], b = v[i + h];
        v[i] = a + b;
        v[i + h] = a - b;
      }
    }
  }
}

DEVFN int padi(int i) { return i + (i >> 4) + (i >> 8); }  // conflict-free LDS pad

// MODE 0: in = x (f32), multiply sgn (SU) BEFORE transform, write bf16 (x 1/64).
// MODE 1: in = f32 (d_out in place), multiply sgn (SV) AFTER transform, write f32.
// 4 rows per block; next-row global loads prefetched under round-3 compute.
template<int MODE>
__global__ __launch_bounds__(256)
void fwht_rows(const float* in, const float* __restrict__ sgn,
               __bf16* __restrict__ outb, float* __restrict__ outf)
{
  __shared__ float s[4366];  // 4096 + pad
  const int t = threadIdx.x;
  const int base1 = t * 17 + (t >> 4);          // == padi(16t)
  const int base2 = (t & 15) + ((t >> 4) << 8);

  float sg[16];
  if (MODE == 0) {
    const f32x4* p = (const f32x4*)(sgn + t * 16);   // SU on load layout
    #pragma unroll
    for (int j4 = 0; j4 < 4; ++j4) {
      f32x4 sv = p[j4];
      #pragma unroll
      for (int q = 0; q < 4; ++q) sg[j4 * 4 + q] = sv[q];
    }
  } else {
    #pragma unroll
    for (int i = 0; i < 16; ++i) sg[i] = sgn[t + (i << 8)];  // SV on store layout
  }

  float v[16], w[16];
  const int row0 = blockIdx.x * 4;
  {
    const f32x4* p = (const f32x4*)(in + (size_t)row0 * 4096 + t * 16);
    #pragma unroll
    for (int j4 = 0; j4 < 4; ++j4) {
      f32x4 xv = p[j4];
      #pragma unroll
      for (int q = 0; q < 4; ++q) v[j4 * 4 + q] = xv[q];
    }
  }

  #pragma unroll 1
  for (int rr = 0; rr < 4; ++rr) {
    const int row = row0 + rr;
    if (MODE == 0) {
      #pragma unroll
      for (int i = 0; i < 16; ++i) v[i] *= sg[i];
    }
    fwht16(v);                                   // bits 0-3
    #pragma unroll
    for (int j = 0; j < 16; ++j) s[base1 + j] = v[j];
    __syncthreads();

    #pragma unroll
    for (int i = 0; i < 16; ++i) v[i] = s[padi(base2 + (i << 4))];
    fwht16(v);                                   // bits 4-7
    #pragma unroll
    for (int i = 0; i < 16; ++i) s[padi(base2 + (i << 4))] = v[i];
    __syncthreads();

    #pragma unroll
    for (int i = 0; i < 16; ++i) w[i] = s[padi(t + (i << 8))];

    if (rr < 3) {                                // prefetch next row into v
      const f32x4* p = (const f32x4*)(in + (size_t)(row + 1) * 4096 + t * 16);
      #pragma unroll
      for (int j4 = 0; j4 < 4; ++j4) {
        f32x4 xv = p[j4];
        #pragma unroll
        for (int q = 0; q < 4; ++q) v[j4 * 4 + q] = xv[q];
      }
    }

    fwht16(w);                                   // bits 8-11
    if (MODE == 0) {
      #pragma unroll
      for (int i = 0; i < 16; ++i)
        outb[(size_t)row * 4096 + t + (i << 8)] = (__bf16)(w[i] * 0.015625f);
    } else {
      #pragma unroll
      for (int i = 0; i < 16; ++i)
        outf[(size_t)row * 4096 + t + (i << 8)] = w[i] * 0.015625f * sg[i];
    }
    __syncthreads();                             // protect LDS reuse
  }
}

// ---------------- build Ut[4096][128], Vt[4096][128] (bf16) ----------------
__global__ __launch_bounds__(256)
void prep_uv(const float* __restrict__ grid8,
             const float* __restrict__ Lft, const float* __restrict__ Rft,
             const int* __restrict__ Lidx, const int* __restrict__ Ridx,
             __bf16* __restrict__ Ut, __bf16* __restrict__ Vt)
{
  int tid = blockIdx.x * 256 + threadIdx.x;
  const int half = 4096 * 128;
  bool isV = tid >= half;
  int e = isV ? tid - half : tid;
  int j = e >> 7;
  int r = e & 127;
  float v;
  if (!isV) {
    if (r < 64) v = 1.1f * grid8[(size_t)Lidx[r * 512 + (j >> 3)] * 8 + (j & 7)];
    else        v = Lft[(size_t)j * 64 + (r - 64)];
    Ut[e] = (__bf16)v;
  } else {
    if (r < 64) v = 1.05f * grid8[(size_t)Ridx[r * 512 + (j >> 3)] * 8 + (j & 7)];
    else        v = Rft[(size_t)(r - 64) * 4096 + j];
    Vt[e] = (__bf16)v;
  }
}

// ---------------- combine GEMM (proven m97-style, K=128): W' builder --------
template<int K>
__global__ __launch_bounds__(256)
void gemm_bt(const __bf16* __restrict__ A, const __bf16* __restrict__ B,
             __bf16* __restrict__ Cb,
             const int* __restrict__ Qidx, const float* __restrict__ grid8,
             int Nn, int nbx)
{
  __shared__ __bf16 sA[128 * 64];
  __shared__ __bf16 sB[128 * 64];

  const int nwg = gridDim.x;
  const int orig = blockIdx.x;
  const int cpx = nwg >> 3;
  const int wg = (orig & 7) * cpx + (orig >> 3);
  const int bm = wg / nbx, bn = wg % nbx;

  const int t = threadIdx.x;
  const int lane = t & 63;
  const int w = t >> 6;
  const int wr = w >> 1, wc = w & 1;

  const int aRow0 = bm * 128;
  const int bRow0 = bn * 128;

  f32x4 acc[4][4] = {};

  #pragma unroll 1
  for (int k0 = 0; k0 < K; k0 += 64) {
    #pragma unroll
    for (int i = 0; i < 4; ++i) {
      int u = i * 256 + t;
      int rowu = u >> 3, cs = u & 7;
      int c = cs ^ (rowu & 7);
      async_g2l16(A + (size_t)(aRow0 + rowu) * K + k0 + c * 8, &sA[u * 8]);
      async_g2l16(B + (size_t)(bRow0 + rowu) * K + k0 + c * 8, &sB[u * 8]);
    }
    asm volatile("s_waitcnt vmcnt(0)" ::: "memory");
    __syncthreads();

    bf16x8 a[4][2], b[4][2];
    #pragma unroll
    for (int m = 0; m < 4; ++m) {
      #pragma unroll
      for (int kk = 0; kk < 2; ++kk) {
        int c = kk * 4 + (lane >> 4);
        int rowA = wr * 64 + m * 16 + (lane & 15);
        int uA = rowA * 8 + (c ^ (rowA & 7));
        a[m][kk] = *(const bf16x8*)&sA[uA * 8];
        int rowB = wc * 64 + m * 16 + (lane & 15);
        int uB = rowB * 8 + (c ^ (rowB & 7));
        b[m][kk] = *(const bf16x8*)&sB[uB * 8];
      }
    }
    #pragma unroll
    for (int kk = 0; kk < 2; ++kk)
      #pragma unroll
      for (int m = 0; m < 4; ++m)
        #pragma unroll
        for (int n = 0; n < 4; ++n)
          acc[m][n] = __builtin_amdgcn_mfma_f32_16x16x32_bf16(
              a[m][kk], b[n][kk], acc[m][n], 0, 0, 0);
    __syncthreads();
  }

  #pragma unroll
  for (int m = 0; m < 4; ++m) {
    #pragma unroll
    for (int n = 0; n < 4; ++n) {
      int gr = aRow0 + wr * 64 + m * 16 + ((lane >> 4) << 2);
      int gc = bRow0 + wc * 64 + n * 16 + (lane & 15);
      #pragma unroll
      for (int q = 0; q < 4; ++q) {
        float v = acc[m][n][q];
        int idx = Qidx[(size_t)(gr + q) * (Nn >> 3) + (gc >> 3)];
        v += 0.9f * grid8[(size_t)idx * 8 + (gc & 7)];
        Cb[(size_t)(gr + q) * Nn + gc] = (__bf16)v;
      }
    }
  }
}

// ---------------- main GEMM: 256x256, BK=64, 8-phase, counted vmcnt ---------
// C[M,N] = A[M,K]*B[N,K]^T, f32 out. 512 threads = 8 waves (2M x 4N), wave
// tile 128x64. LDS ping-pong: 2 x (A 32K + B 32K) = 128 KiB.
// Per K-tile, 4 phases:
//   P0: ds a[0..3][*] + b[0..1][*] (12 rd) | bar | lgkm0 | 16 MFMA Q(m0-3,n0-1) | bar
//   P1: ds a[4..7][*] + b[2..3][*] (12 rd) | bar | lgkm0 | 16 MFMA Q(m0-3,n2-3) | bar
//   P2: stage A(t+2) (4 gload)             | bar |         16 MFMA Q(m4-7,n0-1) | bar
//   P3: stage B(t+2) (4 gload)             | bar |         16 MFMA Q(m4-7,n2-3) |
//   end: vmcnt(8) (t+1 resident, t+2's 8 in flight) | bar
// Safety: stage(t+2) writes buf[t&1] only after P1-close barrier, by which all
// waves' ds_reads of that buffer have drained (own lgkmcnt(0) precedes arrival).
// LDS unit u=row*8+slot, slot=(kk*4+k8l)^(row&7); inverse swizzle on global src.
template<int NT>   // K = NT*64
__global__ __launch_bounds__(512, 2)
void gemm256_8p(const __bf16* __restrict__ A, const __bf16* __restrict__ B,
                float* __restrict__ Cf, int Nn, int nbx)
{
  constexpr int K = NT * 64;
  __shared__ __bf16 lds[2 * 32768];     // [buf][A|B] 16384 bf16 each half

  const int nwg = gridDim.x;            // divisible by 8
  const int orig = blockIdx.x;
  const int cpx = nwg >> 3;
  const int wg = (orig & 7) * cpx + (orig >> 3);
  const int bm = wg / nbx, bn = wg % nbx;

  const int tid = threadIdx.x;
  const int lane = tid & 63;
  const int wid = tid >> 6;
  const int wm = wid >> 2;              // 0..1
  const int wn = wid & 3;               // 0..3

  const int aRow0 = bm * 256;
  const int bRow0 = bn * 256;

  const int k8l = lane >> 4;            // 0..3
  const int rl = lane & 15;

  auto stageA = [&](int t) {
    __bf16* d = &lds[(t & 1) * 32768];
    const __bf16* g = A + (size_t)aRow0 * K + t * 64;
    #pragma unroll
    for (int i = 0; i < 4; ++i) {
      int u = i * 512 + tid;
      int row = u >> 3, slot = u & 7;
      int chunk = slot ^ (row & 7);
      async_g2l16(g + (size_t)row * K + chunk * 8, d + u * 8);
    }
  };
  auto stageB = [&](int t) {
    __bf16* d = &lds[(t & 1) * 32768 + 16384];
    const __bf16* g = B + (size_t)bRow0 * K + t * 64;
    #pragma unroll
    for (int i = 0; i < 4; ++i) {
      int u = i * 512 + tid;
      int row = u >> 3, slot = u & 7;
      int chunk = slot ^ (row & 7);
      async_g2l16(g + (size_t)row * K + chunk * 8, d + u * 8);
    }
  };

  f32x4 acc[8][4] = {};

  // prologue: tiles 0,1; wait tile 0 (tile 1's 8 loads stay in flight)
  stageA(0); stageB(0); stageA(1); stageB(1);
  asm volatile("s_waitcnt vmcnt(8)" ::: "memory");
  __builtin_amdgcn_sched_barrier(0);
  __builtin_amdgcn_s_barrier();
  __builtin_amdgcn_sched_barrier(0);

  bf16x8 a[8][2], b[4][2];

  #pragma unroll 1
  for (int t = 0; t < NT; ++t) {
    const __bf16* bufA = &lds[(t & 1) * 32768];
    const __bf16* bufB = &lds[(t & 1) * 32768 + 16384];

    // ---- P0: ds a[0..3], b[0..1]; MFMA Q(m0-3, n0-1)
    #pragma unroll
    for (int m = 0; m < 4; ++m)
      #pragma unroll
      for (int kk = 0; kk < 2; ++kk) {
        int row = wm * 128 + m * 16 + rl;
        int slot = (kk * 4 + k8l) ^ (row & 7);
        a[m][kk] = *(const bf16x8*)(bufA + (row * 8 + slot) * 8);
      }
    #pragma unroll
    for (int n = 0; n < 2; ++n)
      #pragma unroll
      for (int kk = 0; kk < 2; ++kk) {
        int row = wn * 64 + n * 16 + rl;
        int slot = (kk * 4 + k8l) ^ (row & 7);
        b[n][kk] = *(const bf16x8*)(bufB + (row * 8 + slot) * 8);
      }
    __builtin_amdgcn_s_barrier();
    asm volatile("s_waitcnt lgkmcnt(0)" ::: "memory");
    __builtin_amdgcn_sched_barrier(0);
    __builtin_amdgcn_s_setprio(1);
    #pragma unroll
    for (int kk = 0; kk < 2; ++kk)
      #pragma unroll
      for (int m = 0; m < 4; ++m)
        #pragma unroll
        for (int n = 0; n < 2; ++n)
          acc[m][n] = __builtin_amdgcn_mfma_f32_16x16x32_bf16(
              a[m][kk], b[n][kk], acc[m][n], 0, 0, 0);
    __builtin_amdgcn_s_setprio(0);
    __builtin_amdgcn_s_barrier();

    // ---- P1: ds a[4..7], b[2..3]; MFMA Q(m0-3, n2-3)
    #pragma unroll
    for (int m = 4; m < 8; ++m)
      #pragma unroll
      for (int kk = 0; kk < 2; ++kk) {
        int row = wm * 128 + m * 16 + rl;
        int slot = (kk * 4 + k8l) ^ (row & 7);
        a[m][kk] = *(const bf16x8*)(bufA + (row * 8 + slot) * 8);
      }
    #pragma unroll
    for (int n = 2; n < 4; ++n)
      #pragma unroll
      for (int kk = 0; kk < 2; ++kk) {
        int row = wn * 64 + n * 16 + rl;
        int slot = (kk * 4 + k8l) ^ (row & 7);
        b[n][kk] = *(const bf16x8*)(bufB + (row * 8 + slot) * 8);
      }
    __builtin_amdgcn_s_barrier();
    asm volatile("s_waitcnt lgkmcnt(0)" ::: "memory");
    __builtin_amdgcn_sched_barrier(0);
    __builtin_amdgcn_s_setprio(1);
    #pragma unroll
    for (int kk = 0; kk < 2; ++kk)
      #pragma unroll
      for (int m = 0; m < 4; ++m)
        #pragma unroll
        for (int n = 2; n < 4; ++n)
          acc[m][n] = __builtin_amdgcn_mfma_f32_16x16x32_bf16(
              a[m][kk], b[n][kk], acc[m][n], 0, 0, 0);
    __builtin_amdgcn_s_setprio(0);
    __builtin_amdgcn_s_barrier();

    // ---- P2: stage A(t+2); MFMA Q(m4-7, n0-1)
    __builtin_amdgcn_sched_barrier(0);
    if (t + 2 < NT) stageA(t + 2);
    __builtin_amdgcn_s_barrier();
    __builtin_amdgcn_s_setprio(1);
    #pragma unroll
    for (int kk = 0; kk < 2; ++kk)
      #pragma unroll
      for (int m = 4; m < 8; ++m)
        #pragma unroll
        for (int n = 0; n < 2; ++n)
          acc[m][n] = __builtin_amdgcn_mfma_f32_16x16x32_bf16(
              a[m][kk], b[n][kk], acc[m][n], 0, 0, 0);
    __builtin_amdgcn_s_setprio(0);
    __builtin_amdgcn_s_barrier();

    // ---- P3: stage B(t+2); MFMA Q(m4-7, n2-3)
    __builtin_amdgcn_sched_barrier(0);
    if (t + 2 < NT) stageB(t + 2);
    __builtin_amdgcn_s_barrier();
    __builtin_amdgcn_s_setprio(1);
    #pragma unroll
    for (int kk = 0; kk < 2; ++kk)
      #pragma unroll
      for (int m = 4; m < 8; ++m)
        #pragma unroll
        for (int n = 2; n < 4; ++n)
          acc[m][n] = __builtin_amdgcn_mfma_f32_16x16x32_bf16(
              a[m][kk], b[n][kk], acc[m][n], 0, 0, 0);
    __builtin_amdgcn_s_setprio(0);

    // ---- end of iter: ensure tile t+1 resident; keep t+2's 8 in flight
    if (t + 2 < NT)      asm volatile("s_waitcnt vmcnt(8)" ::: "memory");
    else if (t + 1 < NT) asm volatile("s_waitcnt vmcnt(0)" ::: "memory");
    __builtin_amdgcn_sched_barrier(0);
    __builtin_amdgcn_s_barrier();
    __builtin_amdgcn_sched_barrier(0);
  }

  // epilogue: C/D layout col=lane&15, row=(lane>>4)*4+q
  #pragma unroll
  for (int m = 0; m < 8; ++m) {
    #pragma unroll
    for (int n = 0; n < 4; ++n) {
      int gr = aRow0 + wm * 128 + m * 16 + ((lane >> 4) << 2);
      int gc = bRow0 + wn * 64 + n * 16 + rl;
      #pragma unroll
      for (int q = 0; q < 4; ++q)
        Cf[(size_t)(gr + q) * Nn + gc] = acc[m][n][q];
    }
  }
}

// ---------------------------------------------------------------------------
extern "C" void kernel_launch(void* const* d_in, const int* in_sizes, int n_in,
                              void* d_out, int out_size, void* d_ws, size_t ws_size,
                              hipStream_t stream) {
  const float* x    = (const float*)d_in[0];
  const float* SU   = (const float*)d_in[1];
  const float* SV   = (const float*)d_in[2];
  const float* grid = (const float*)d_in[3];
  const float* Lft  = (const float*)d_in[4];
  const float* Rft  = (const float*)d_in[5];
  const int*   Qidx = (const int*)d_in[6];
  const int*   Ridx = (const int*)d_in[7];
  const int*   Lidx = (const int*)d_in[8];
  float* out = (float*)d_out;

  char* ws = (char*)d_ws;
  __bf16* xh = (__bf16*)ws;                               // 8192x4096 bf16 = 64 MiB
  __bf16* Wc = (__bf16*)(ws + ((size_t)64 << 20));        // 4096x4096 bf16 = 32 MiB
  __bf16* Ut = (__bf16*)(ws + ((size_t)96 << 20));        // 4096x128  bf16 =  1 MiB
  __bf16* Vt = (__bf16*)(ws + ((size_t)97 << 20));        // 4096x128  bf16 =  1 MiB

  // 1. low-rank factors -> Ut, Vt
  prep_uv<<<4096, 256, 0, stream>>>(grid, Lft, Rft, Lidx, Ridx, Ut, Vt);
  // 2. xh = FWHT(x * SU), bf16
  fwht_rows<0><<<2048, 256, 0, stream>>>(x, SU, xh, nullptr);
  // 3. W' = Ut @ Vt^T + 0.9*dequant(Wq)  (bf16)
  gemm_bt<128><<<1024, 256, 0, stream>>>(Ut, Vt, Wc, Qidx, grid, 4096, 32);
  // 4. out = xh @ W'^T (f32), 256^2 8-phase pipeline
  gemm256_8p<64><<<512, 512, 0, stream>>>(xh, Wc, out, 4096, 16);
  // 5. out = FWHT(out) * SV, in place
  fwht_rows<1><<<2048, 256, 0, stream>>>(out, SV, nullptr, out);
}